// Round 8
// baseline (367.639 us; speedup 1.0000x reference)
//
#include <hip/hip_runtime.h>

typedef float f32x4 __attribute__((ext_vector_type(4)));
typedef short bf16x8 __attribute__((ext_vector_type(8)));
typedef unsigned int uint;

#define T_LEN 200
#define E_DIM 64
#define H1D 80
#define H2D 40
#define NT1 5      // 80/16 col tiles GEMM1
#define NT2 3      // 48/16 col tiles GEMM2
// ---- ws byte offsets (all rewritten every launch) ----
#define WS_BC    0u        // f32[5][2][64][8]  = 20480 B   (W1_B - W1_C, frag layout)
#define WS_D     20480u    // f32[5][2][64][8]  = 20480 B   (W1_D, frag layout)
#define WS_W2    40960u    // bf16[3][3][64][8] = 9216 B    (W2 padded 96x48, frag layout)
#define WS_W1EFF 50176u    // f32[64][80]       = 20480 B   (W1_A + W1_C)

static __device__ __forceinline__ unsigned short f2bf(float x) {
  unsigned u = __builtin_bit_cast(unsigned, x);
  return (unsigned short)((u + 0x7fffu + ((u >> 16) & 1u)) >> 16);
}
static __device__ __forceinline__ uint pkbf(float lo, float hi) {
  return ((uint)f2bf(hi) << 16) | (uint)f2bf(lo);
}
static __device__ __forceinline__ float sigm(float x) {
  return __builtin_amdgcn_rcpf(1.f + __expf(-x));
}

// ---------------- setup 1: weight fragments (coalesced, once per launch) ----------------
__global__ __launch_bounds__(256)
void setup1(const float* __restrict__ W1, const float* __restrict__ W2,
            unsigned char* __restrict__ ws) {
  float* bc = (float*)(ws + WS_BC);
  float* dd = (float*)(ws + WS_D);
  unsigned short* w2f = (unsigned short*)(ws + WS_W2);
  float* w1e = (float*)(ws + WS_W1EFF);
  int g = blockIdx.x * 256 + threadIdx.x;
  if (g < 5120) {                       // BC + D fragments
    int nt = g >> 10;
    int rem = g & 1023;
    int ks = rem >> 9;
    int l = (rem >> 3) & 63;
    int j = g & 7;
    int e = ks * 32 + ((l >> 4) << 3) + j;
    int col = nt * 16 + (l & 15);
    bc[g] = W1[(64 + e) * H1D + col] - W1[(128 + e) * H1D + col];
    dd[g] = W1[(192 + e) * H1D + col];
  } else if (g < 9728) {                // W2 fragments (padded to 96x48)
    int h = g - 5120;
    int nt2 = h / 1536;
    int rem = h - nt2 * 1536;
    int ks2 = rem >> 9;
    int l = (rem >> 3) & 63;
    int j = h & 7;
    int k = ks2 * 32 + ((l >> 4) << 3) + j;
    int n = nt2 * 16 + (l & 15);
    float v = (k < H1D && n < H2D) ? W2[k * H2D + n] : 0.f;
    w2f[h] = f2bf(v);
  } else if (g < 14848) {               // W1eff = A + C
    int w = g - 9728;
    int e = w / 80;
    int j = w - e * 80;
    w1e[w] = W1[e * H1D + j] + W1[(128 + e) * H1D + j];
  }
}

// ---------------- main: one block (8 waves) per b ----------------
// LDS: H1 per-wave [8][16 rows][160B] XOR-swz (20480) | FR frags (10240, aliased PP) | SC (832) | B1 (320)
#define OFF_H1 0
#define OFF_FR 20480
#define OFF_SC 30720
#define OFF_B1 31552
#define SMEM_TOTAL 31872

__global__ __launch_bounds__(512, 2)
void din_main(const float* __restrict__ query, const float* __restrict__ keys,
              const int* __restrict__ keys_length,
              const float* __restrict__ b1, const float* __restrict__ b2,
              const float* __restrict__ Wd, const float* __restrict__ bd,
              const unsigned char* __restrict__ ws, float* __restrict__ out) {
  __shared__ __align__(16) unsigned char smem[SMEM_TOTAL];
  unsigned short* FR = (unsigned short*)(smem + OFF_FR);
  float* SC = (float*)(smem + OFF_SC);
  float* B1 = (float*)(smem + OFF_B1);
  float* PP = (float*)(smem + OFF_FR);   // alias: FR dead after GEMM1 of last tile

  const int tid = threadIdx.x, b = blockIdx.x;
  const int lane = tid & 63, wv = tid >> 6;
  const int qq = lane >> 4, cc = lane & 15;
  const float* keyb = keys + (size_t)b * (T_LEN * E_DIM);
  const float* qrow = query + (size_t)b * E_DIM;

  // ---- preload GEMM1 A-fragments for both tiles straight from global ----
  bf16x8 afr[2][2];   // [ti][ks]
  #pragma unroll
  for (int ti = 0; ti < 2; ++ti) {
    const int tt = wv + ti * 8;
    const int row = tt * 16 + cc;
    #pragma unroll
    for (int ks = 0; ks < 2; ++ks) {
      if (tt < 13 && row < T_LEN) {
        const float4 va = *(const float4*)(keyb + row * E_DIM + ks * 32 + qq * 8);
        const float4 vb = *(const float4*)(keyb + row * E_DIM + ks * 32 + qq * 8 + 4);
        uint4 u;
        u.x = pkbf(va.x, va.y);
        u.y = pkbf(va.z, va.w);
        u.z = pkbf(vb.x, vb.y);
        u.w = pkbf(vb.z, vb.w);
        afr[ti][ks] = __builtin_bit_cast(bf16x8, u);
      } else {
        afr[ti][ks] = bf16x8{0, 0, 0, 0, 0, 0, 0, 0};
      }
    }
  }

  // ---- cooperative GEMM1 B-fragment build into LDS (pairs; BC/D read once/block) ----
  {
    const float* wsBC = (const float*)(ws + WS_BC);
    const float* wsD  = (const float*)(ws + WS_D);
    #pragma unroll
    for (int i = 0; i < 5; ++i) {
      int f = (i * 512 + tid) * 2;
      int j = f & 7, l = (f >> 3) & 63, ks = (f >> 9) & 1;
      int e = ks * 32 + ((l >> 4) << 3) + j;
      const float2 bc = *(const float2*)(wsBC + f);
      const float2 dd = *(const float2*)(wsD + f);
      *(uint*)(FR + f) = pkbf(bc.x + qrow[e] * dd.x, bc.y + qrow[e + 1] * dd.y);
    }
  }

  // ---- bias1 = q @ W1eff + b1 (threads 0..79, overlapped with other waves' FR) ----
  if (tid < H1D) {
    const float* w1e = (const float*)(ws + WS_W1EFF);
    float s = b1[tid];
    #pragma unroll
    for (int e = 0; e < E_DIM; ++e) s += qrow[e] * w1e[e * H1D + tid];
    B1[tid] = s;
  }

  float b2c[NT2], wdl[NT2];
  #pragma unroll
  for (int nt = 0; nt < NT2; ++nt) {
    int col = nt * 16 + cc;
    b2c[nt] = (col < H2D) ? b2[col] : 0.f;
    wdl[nt] = (col < H2D) ? Wd[col] : 0.f;
  }
  const float bdv = bd[0];
  const int len = keys_length[b];

  __syncthreads();   // FR + B1 ready

  float bia[NT1];
  #pragma unroll
  for (int nt = 0; nt < NT1; ++nt) bia[nt] = B1[nt * 16 + cc];

  const unsigned short* wsW2 = (const unsigned short*)(ws + WS_W2);
  unsigned char* H1w = smem + OFF_H1 + wv * 2560;   // 16 rows x 160B per wave

  #pragma unroll 1
  for (int ti = 0; ti < 2; ++ti) {
    const int tt = wv + ti * 8;
    if (tt < 13) {
      f32x4 accs[NT1];
      #pragma unroll
      for (int nt = 0; nt < NT1; ++nt) {
        bf16x8 bf0 = *(const bf16x8*)(FR + ((nt * 2 + 0) * 64 + lane) * 8);
        bf16x8 bf1 = *(const bf16x8*)(FR + ((nt * 2 + 1) * 64 + lane) * 8);
        f32x4 a = {bia[nt], bia[nt], bia[nt], bia[nt]};
        a = __builtin_amdgcn_mfma_f32_16x16x32_bf16(afr[ti][0], bf0, a, 0, 0, 0);
        a = __builtin_amdgcn_mfma_f32_16x16x32_bf16(afr[ti][1], bf1, a, 0, 0, 0);
        accs[nt] = a;
      }
      // sigmoid -> H1 wave-private [rloc][80] bf16, XOR-swz on 160B pitch (pair cvt)
      #pragma unroll
      for (int nt = 0; nt < NT1; ++nt) {
        #pragma unroll
        for (int r = 0; r < 4; r += 2) {
          uint pk = pkbf(sigm(accs[nt][r]), sigm(accs[nt][r + 1]));
          int r0 = qq * 4 + r, r1 = r0 + 1;
          unsigned by0 = ((unsigned)(r0 * 160 + (nt * 16 + cc) * 2)) ^ ((unsigned)(r0 & 7) << 4);
          unsigned by1 = ((unsigned)(r1 * 160 + (nt * 16 + cc) * 2)) ^ ((unsigned)(r1 & 7) << 4);
          *(unsigned short*)(H1w + by0) = (unsigned short)pk;
          *(unsigned short*)(H1w + by1) = (unsigned short)(pk >> 16);
        }
      }
      // GEMM2 A-frags from own wave's H1 rows
      const unsigned hsw = ((unsigned)cc & 7u) << 4;
      const unsigned hb = (unsigned)cc * 160;
      bf16x8 h0 = *(const bf16x8*)(H1w + ((hb + qq * 16) ^ hsw));
      bf16x8 h1 = *(const bf16x8*)(H1w + ((hb + 64 + qq * 16) ^ hsw));
      bf16x8 h2 = {0, 0, 0, 0, 0, 0, 0, 0};
      if (qq < 2) h2 = *(const bf16x8*)(H1w + ((hb + 128 + qq * 16) ^ hsw));
      float vr[4] = {0.f, 0.f, 0.f, 0.f};
      #pragma unroll
      for (int nt = 0; nt < NT2; ++nt) {
        bf16x8 w0 = *(const bf16x8*)(wsW2 + ((nt * 3 + 0) * 64 + lane) * 8);
        bf16x8 w1 = *(const bf16x8*)(wsW2 + ((nt * 3 + 1) * 64 + lane) * 8);
        bf16x8 w2 = *(const bf16x8*)(wsW2 + ((nt * 3 + 2) * 64 + lane) * 8);
        f32x4 a = {b2c[nt], b2c[nt], b2c[nt], b2c[nt]};
        a = __builtin_amdgcn_mfma_f32_16x16x32_bf16(h0, w0, a, 0, 0, 0);
        a = __builtin_amdgcn_mfma_f32_16x16x32_bf16(h1, w1, a, 0, 0, 0);
        a = __builtin_amdgcn_mfma_f32_16x16x32_bf16(h2, w2, a, 0, 0, 0);
        #pragma unroll
        for (int r = 0; r < 4; ++r) vr[r] += sigm(a[r]) * wdl[nt];
      }
      #pragma unroll
      for (int r = 0; r < 4; ++r) {
        float v = vr[r];
        v += __shfl_xor(v, 1);
        v += __shfl_xor(v, 2);
        v += __shfl_xor(v, 4);
        v += __shfl_xor(v, 8);
        if (cc == 0) {
          int t = tt * 16 + qq * 4 + r;
          SC[t] = (t < len) ? (bdv + v) : 0.f;
        }
      }
    }
  }
  __syncthreads();   // SC complete; FR region now reusable as PP

  // ---- pooling from global keys (L2-hot): out[b][e] = sum_t SC[t]*keys[b][t][e] ----
  {
    const int e = lane;
    float accp = 0.f;
    #pragma unroll
    for (int i = 0; i < 25; ++i) {
      int t = wv + i * 8;
      accp += SC[t] * keyb[t * E_DIM + e];
    }
    PP[tid] = accp;
  }
  __syncthreads();
  if (tid < E_DIM) {
    float s = 0.f;
    #pragma unroll
    for (int w = 0; w < 8; ++w) s += PP[w * 64 + tid];
    out[(size_t)b * E_DIM + tid] = s;
  }
}

extern "C" void kernel_launch(void* const* d_in, const int* in_sizes, int n_in,
                              void* d_out, int out_size, void* d_ws, size_t ws_size,
                              hipStream_t stream) {
  const float* query = (const float*)d_in[0];
  const float* keys  = (const float*)d_in[1];
  const int*   klen  = (const int*)d_in[2];
  const float* W1 = (const float*)d_in[3];
  const float* b1 = (const float*)d_in[4];
  const float* W2 = (const float*)d_in[5];
  const float* b2 = (const float*)d_in[6];
  const float* Wd = (const float*)d_in[7];
  const float* bd = (const float*)d_in[8];
  float* out = (float*)d_out;
  const int B = in_sizes[2];
  unsigned char* ws = (unsigned char*)d_ws;

  hipLaunchKernelGGL(setup1, dim3(58), dim3(256), 0, stream, W1, W2, ws);
  hipLaunchKernelGGL(din_main, dim3(B), dim3(512), 0, stream,
                     query, keys, klen, b1, b2, Wd, bd, ws, out);
}